// Round 16
// baseline (197.147 us; speedup 1.0000x reference)
//
#include <hip/hip_runtime.h>
#include <hip/hip_bf16.h>

typedef __attribute__((ext_vector_type(8))) short bf16x8;
typedef __attribute__((ext_vector_type(4))) float f32x4;

#define MFMA16(a, b, c) __builtin_amdgcn_mfma_f32_16x16x32_bf16((a), (b), (c), 0, 0, 0)

#define LDQ 4352  // fused qkv row stride (2048+2048+128+128)
// K columns are pre-scaled by 1/sqrt(128)*log2(e) in the QKV GEMM epilogue,
// so attention probabilities are exp2(s) = v_exp_f32(s) directly.
#define KSCALE 0.12751743f

__device__ __forceinline__ ushort f2bf(float f) {
    unsigned int x = __float_as_uint(f);
    x += 0x7fffu + ((x >> 16) & 1u);
    return (ushort)(x >> 16);
}
__device__ __forceinline__ float bf2f(ushort u) {
    return __uint_as_float(((unsigned int)u) << 16);
}
__device__ __forceinline__ float exp2_fast(float x) {
    float r;
    asm("v_exp_f32 %0, %1" : "=v"(r) : "v"(x));
    return r;
}
__device__ __forceinline__ unsigned int cvtpk(float lo, float hi) {
    unsigned int r;
    asm("v_cvt_pk_bf16_f32 %0, %1, %2" : "=v"(r) : "v"(lo), "v"(hi));
    return r;
}

__device__ __forceinline__ void gload16(const ushort* g, ushort* l) {
    __builtin_amdgcn_global_load_lds((const __attribute__((address_space(1))) unsigned int*)g,
                                     (__attribute__((address_space(3))) unsigned int*)l, 16, 0, 0);
}

// ---------------- fused preprocessing: cvt(x) + 5 weight transposes ----------------
__global__ __launch_bounds__(256) void prep_k(const float* __restrict__ x, ushort* __restrict__ xb,
                                              const float* __restrict__ q1w, const float* __restrict__ q2w,
                                              const float* __restrict__ kw, const float* __restrict__ vw,
                                              const float* __restrict__ ow,
                                              ushort* __restrict__ w1t, ushort* __restrict__ w2t,
                                              ushort* __restrict__ wkt, ushort* __restrict__ wvt,
                                              ushort* __restrict__ wot) {
    int bid = blockIdx.x;
    if (bid < 4096) {
        int i = bid * 256 + threadIdx.x;
        float4 v = ((const float4*)x)[i];
        ushort4 u;
        u.x = f2bf(v.x); u.y = f2bf(v.y); u.z = f2bf(v.z); u.w = f2bf(v.w);
        ((ushort4*)xb)[i] = u;
        return;
    }
    bid -= 4096;
    const float* in;
    ushort* out;
    int C, TX;
    if (bid < 4096) { in = q1w; out = w1t; C = 2048; TX = 64; }
    else if (bid < 8192) { bid -= 4096; in = q2w; out = w2t; C = 2048; TX = 64; }
    else if (bid < 12288) { bid -= 8192; in = ow; out = wot; C = 2048; TX = 64; }
    else if (bid < 12544) { bid -= 12288; in = kw; out = wkt; C = 128; TX = 4; }
    else { bid -= 12544; in = vw; out = wvt; C = 128; TX = 4; }
    __shared__ ushort t[32][33];
    const int c0 = (bid % TX) * 32, r0 = (bid / TX) * 32;
    const int lx = threadIdx.x & 31, ly = threadIdx.x >> 5;
#pragma unroll
    for (int i = 0; i < 4; ++i)
        t[ly + i * 8][lx] = f2bf(in[(size_t)(r0 + ly + i * 8) * C + c0 + lx]);
    __syncthreads();
    const int sc = threadIdx.x & 15;
    const int sr = threadIdx.x >> 4;
#pragma unroll
    for (int j = 0; j < 2; ++j) {
        const int cc = sr + j * 16;
        unsigned int w = (unsigned int)t[2 * sc][cc] | ((unsigned int)t[2 * sc + 1][cc] << 16);
        *(unsigned int*)&out[(size_t)(c0 + cc) * 2048 + r0 + 2 * sc] = w;
    }
}

// ---------------- QKV GEMM: 64x128 tile -> 1088 blocks = 4.25/CU ----------------
// Cross-block residency is the dominant lever (measured: 1/CU=58.7us vs 2/CU=~37us for
// identical work). Same proven BK=32 2-buffer loop; N stays 128-wide so RoPE pair
// (d,d+64) and V-transpose remain wave-local. 24KB LDS + launch_bounds(512,8) -> 4
// resident blocks/CU (32 waves, full). A 64x32 staged by waves 0-3; B 128x32 by all 8.
__global__ __launch_bounds__(512, 8) void gemmqkv_k(const ushort* __restrict__ A,
                                                    const ushort* __restrict__ Bt,
                                                    ushort* __restrict__ C,
                                                    const float* __restrict__ cs,
                                                    const float* __restrict__ sn,
                                                    ushort* __restrict__ vtb) {
    __shared__ ushort As[2 * 2048];  // [buf][64 rows][32 cols]
    __shared__ ushort Bs[2 * 4096];  // [buf][128 rows][32 cols]
    const int tid = threadIdx.x;
    const int lane = tid & 63, wid = tid >> 6;
    const int cpx = (int)gridDim.x >> 3;  // 136
    const int swz = ((int)blockIdx.x & 7) * cpx + ((int)blockIdx.x >> 3);
    const int nt = swz >> 5;
    const int m0 = (swz & 31) * 64, n0 = nt * 128;
    const int wr = wid >> 2, wc = wid & 3;
    const int l15 = lane & 15, lhi = lane >> 4;

    // B staging: all 8 waves; thread -> row tid>>2 (0..127), slot tid&3; source
    // col pre-swizzled (slot ^= (row>>1)&3); LDS dest linear (rule #21).
    const int brow = tid >> 2;
    const int bcol = (((tid & 3) ^ ((brow >> 1) & 3)) << 3);
    const ushort* gB = Bt + (size_t)(n0 + brow) * 2048 + bcol;
    ushort* lB = &Bs[wid * 512];
    // A staging: waves 0-3; row wid*16 + lane>>2 (0..63), slot lane&3.
    const int arow = wid * 16 + (lane >> 2);
    const int acol = (((lane & 3) ^ ((arow >> 1) & 3)) << 3);
    const ushort* gA = A + (size_t)(m0 + arow) * 2048 + acol;
    ushort* lA = &As[wid * 512];

    f32x4 acc[2][2];
#pragma unroll
    for (int m = 0; m < 2; ++m)
#pragma unroll
        for (int n = 0; n < 2; ++n) acc[m][n] = (f32x4){0.f, 0.f, 0.f, 0.f};

    const int fcol = (lhi << 4) ^ (((l15 >> 1) & 3) << 4);

    gload16(gB, lB);
    if (wid < 4) gload16(gA, lA);
    __syncthreads();

    int cur = 0;
    for (int k0 = 0; k0 < 2048; k0 += 32) {
        if (k0 + 32 < 2048) {  // prefetch next tile; latency hides under compute + co-res blocks
            gload16(gB + k0 + 32, lB + (cur ^ 1) * 4096);
            if (wid < 4) gload16(gA + k0 + 32, lA + (cur ^ 1) * 2048);
        }
        const char* aB = (const char*)&As[cur * 2048];
        const char* bB = (const char*)&Bs[cur * 4096];
        bf16x8 af[2], bfr[2];
#pragma unroll
        for (int m = 0; m < 2; ++m)
            af[m] = *(const bf16x8*)(aB + (wr * 32 + m * 16 + l15) * 64 + fcol);
#pragma unroll
        for (int n = 0; n < 2; ++n)
            bfr[n] = *(const bf16x8*)(bB + (wc * 16 + n * 64 + l15) * 64 + fcol);
#pragma unroll
        for (int m = 0; m < 2; ++m)
#pragma unroll
            for (int n = 0; n < 2; ++n)
                acc[m][n] = MFMA16(af[m], bfr[n], acc[m][n]);
        __syncthreads();
        cur ^= 1;
    }

    if (nt == 33) {
        // V tile -> vtb[128][2048] transposed; rows rb..rb+3 contiguous in vtb
#pragma unroll
        for (int m = 0; m < 2; ++m) {
            const int rb = m0 + wr * 32 + m * 16 + lhi * 4;
#pragma unroll
            for (int n = 0; n < 2; ++n) {
                const int d = wc * 16 + n * 64 + l15;
                uint2 w;
                w.x = cvtpk(acc[m][n][0], acc[m][n][1]);
                w.y = cvtpk(acc[m][n][2], acc[m][n][3]);
                *(uint2*)(vtb + (size_t)d * 2048 + rb) = w;
            }
        }
    } else {
        const float scale = (nt == 32) ? KSCALE : 1.0f;
        const int d0 = wc * 16 + l15;
#pragma unroll
        for (int m = 0; m < 2; ++m) {
            const int rb = m0 + wr * 32 + m * 16 + lhi * 4;
#pragma unroll
            for (int r = 0; r < 4; ++r) {
                const int row = rb + r;
                float c0 = cs[row * 128 + d0], c1 = cs[row * 128 + d0 + 64];
                float s0 = sn[row * 128 + d0], s1 = sn[row * 128 + d0 + 64];
                float t0 = acc[m][0][r], t1 = acc[m][1][r];
                C[(size_t)row * LDQ + n0 + d0] = f2bf((t0 * c0 - t1 * s0) * scale);
                C[(size_t)row * LDQ + n0 + d0 + 64] = f2bf((t1 * c1 + t0 * s1) * scale);
            }
        }
    }
}

// ---------------- out-proj GEMM: 128x64 tile, 512 blocks = 2 blocks/CU ----------------
__global__ __launch_bounds__(512) void gemm_op_k(const ushort* __restrict__ A,
                                                 const ushort* __restrict__ Bt,
                                                 float* __restrict__ C) {
    __shared__ ushort As[2 * 4096];  // [buf][128 rows][32 cols]
    __shared__ ushort Bs[2 * 2048];  // [buf][64 rows][32 cols]
    const int tid = threadIdx.x;
    const int lane = tid & 63, wid = tid >> 6;
    const int cpx = (int)gridDim.x >> 3;  // 64
    const int swz = ((int)blockIdx.x & 7) * cpx + ((int)blockIdx.x >> 3);
    const int m0 = (swz & 15) * 128, n0 = (swz >> 4) * 64;
    const int wr = wid >> 2, wc = wid & 3;
    const int l15 = lane & 15, lhi = lane >> 4;

    const int srow = tid >> 2;
    const int scol = (((tid & 3) ^ ((srow >> 1) & 3)) << 3);
    const ushort* gA = A + (size_t)(m0 + srow) * 2048 + scol;
    ushort* lA = &As[wid * 512];
    const int brow = wid * 16 + (lane >> 2);
    const int bcol = (((lane & 3) ^ ((brow >> 1) & 3)) << 3);
    const ushort* gB = Bt + (size_t)(n0 + brow) * 2048 + bcol;
    ushort* lB = &Bs[wid * 512];

    f32x4 acc[4];
#pragma unroll
    for (int m = 0; m < 4; ++m) acc[m] = (f32x4){0.f, 0.f, 0.f, 0.f};

    const int fcol = (lhi << 4) ^ (((l15 >> 1) & 3) << 4);

    gload16(gA, lA);
    if (wid < 4) gload16(gB, lB);
    __syncthreads();

    int cur = 0;
    for (int k0 = 0; k0 < 2048; k0 += 32) {
        if (k0 + 32 < 2048) {
            gload16(gA + k0 + 32, lA + (cur ^ 1) * 4096);
            if (wid < 4) gload16(gB + k0 + 32, lB + (cur ^ 1) * 2048);
        }
        const char* aB = (const char*)&As[cur * 4096];
        const char* bB = (const char*)&Bs[cur * 2048];
        bf16x8 af[4], bfr;
#pragma unroll
        for (int m = 0; m < 4; ++m)
            af[m] = *(const bf16x8*)(aB + (wr * 64 + m * 16 + l15) * 64 + fcol);
        bfr = *(const bf16x8*)(bB + (wc * 16 + l15) * 64 + fcol);
#pragma unroll
        for (int m = 0; m < 4; ++m)
            acc[m] = MFMA16(af[m], bfr, acc[m]);
        __syncthreads();
        cur ^= 1;
    }

    const int col = n0 + wc * 16 + l15;
#pragma unroll
    for (int m = 0; m < 4; ++m) {
        const int rb = m0 + wr * 64 + m * 16 + lhi * 4;
#pragma unroll
        for (int r = 0; r < 4; ++r)
            C[(size_t)(rb + r) * 2048 + col] = acc[m][r];
    }
}

// ---------------- differential MQA attention (round-12 proven form) ----------------

__device__ __forceinline__ void stage_k_chunk(const ushort* __restrict__ kb, int kc,
                                              ushort* __restrict__ kbuf, int wid, int lane) {
#pragma unroll
    for (int u = 0; u < 2; ++u) {
        const int w = wid * 2 + u;
        const int row = w * 4 + (lane >> 4);
        const int colb = ((lane & 15) * 16) ^ ((row & 7) << 4);
        gload16(kb + (size_t)(kc + row) * LDQ + (colb >> 1), kbuf + w * 512);
    }
}

__device__ __forceinline__ void stage_v_chunk(const ushort* __restrict__ vtb, int kc,
                                              ushort* __restrict__ vbuf, int wid, int lane) {
#pragma unroll
    for (int u = 0; u < 2; ++u) {
        const int w = wid * 2 + u;
        const int rowd = w * 16 + (lane >> 2);
        const int colb = ((lane & 3) * 16) ^ (((rowd >> 1) & 3) << 4);
        gload16(vtb + (size_t)rowd * 2048 + kc + (colb >> 1), vbuf + w * 512);
    }
}

__device__ __forceinline__ void load_k_frags(const ushort* __restrict__ kbuf, int l15, int lhi,
                                             bf16x8 kf[2][4]) {
    const char* kB = (const char*)kbuf;
#pragma unroll
    for (int n2 = 0; n2 < 2; ++n2) {
        const int r = n2 * 16 + l15;
#pragma unroll
        for (int c = 0; c < 4; ++c)
            kf[n2][c] = *(const bf16x8*)(kB + r * 256 + ((lhi * 16 + c * 64) ^ ((r & 7) << 4)));
    }
}

template <bool MASKED>
__device__ __forceinline__ void sums_chunk(const ushort* __restrict__ kbuf, int kc,
                                           int l15, int lhi, int qrow,
                                           const bf16x8* q1f, const bf16x8* q2f,
                                           float& sum1, float& sum2) {
    bf16x8 kf[2][4];
    load_k_frags(kbuf, l15, lhi, kf);
    f32x4 s1[2], s2[2];
#pragma unroll
    for (int n2 = 0; n2 < 2; ++n2) {
        s1[n2] = (f32x4){0.f, 0.f, 0.f, 0.f};
        s2[n2] = (f32x4){0.f, 0.f, 0.f, 0.f};
#pragma unroll
        for (int c = 0; c < 4; ++c) {
            s1[n2] = MFMA16(kf[n2][c], q1f[c], s1[n2]);
            s2[n2] = MFMA16(kf[n2][c], q2f[c], s2[n2]);
        }
    }
    const int kbase = kc + lhi * 4;
#pragma unroll
    for (int n2 = 0; n2 < 2; ++n2)
#pragma unroll
        for (int r = 0; r < 4; ++r) {
            float e1 = exp2_fast(s1[n2][r]);
            float e2 = exp2_fast(s2[n2][r]);
            if (MASKED) {
                bool ok = (kbase + n2 * 16 + r) <= qrow;
                e1 = ok ? e1 : 0.f;
                e2 = ok ? e2 : 0.f;
            }
            sum1 += e1;
            sum2 += e2;
        }
}

__global__ __launch_bounds__(256) void attn_sums_k(const ushort* __restrict__ qkv,
                                                   float* __restrict__ sums) {
    __shared__ ushort Kbuf[2 * 4096];
    const int bid = blockIdx.x;
    const int strip = 127 - (bid >> 3);
    const int cs = (bid >> 2) & 1;
    const int hg = bid & 3;
    const int q0 = strip << 4;
    const int lane = threadIdx.x & 63, wid = threadIdx.x >> 6;
    const int h = hg * 4 + wid;
    const int l15 = lane & 15, lhi = lane >> 4;
    const int qrow = q0 + l15;
    const ushort* kb = qkv + 4096;

    bf16x8 q1f[4], q2f[4];
    {
        size_t base = (size_t)qrow * LDQ + h * 128 + lhi * 8;
#pragma unroll
        for (int c = 0; c < 4; ++c) {
            q1f[c] = *(const bf16x8*)(qkv + base + c * 32);
            q2f[c] = *(const bf16x8*)(qkv + base + 2048 + c * 32);
        }
    }

    const int nchunk = (strip >> 1) + 1;
    const int ndiag = nchunk - 1;
    const int nch = (nchunk - cs + 1) >> 1;

    float sum1 = 0.f, sum2 = 0.f;
    if (nch > 0) stage_k_chunk(kb, cs * 32, Kbuf, wid, lane);
    __syncthreads();
    for (int i = 0; i < nch; ++i) {
        const int ch = cs + 2 * i, kc = ch << 5;
        if (i + 1 < nch) stage_k_chunk(kb, kc + 64, Kbuf + ((i + 1) & 1) * 4096, wid, lane);
        const ushort* kcur = Kbuf + (i & 1) * 4096;
        if (ch == ndiag)
            sums_chunk<true>(kcur, kc, l15, lhi, qrow, q1f, q2f, sum1, sum2);
        else
            sums_chunk<false>(kcur, kc, l15, lhi, qrow, q1f, q2f, sum1, sum2);
        __syncthreads();
    }

    sum1 += __shfl_xor(sum1, 16);
    sum1 += __shfl_xor(sum1, 32);
    sum2 += __shfl_xor(sum2, 16);
    sum2 += __shfl_xor(sum2, 32);

    if (lhi == 0) {
        sums[(size_t)((cs * 2 + 0) * 16 + h) * 2048 + qrow] = sum1;
        sums[(size_t)((cs * 2 + 1) * 16 + h) * 2048 + qrow] = sum2;
    }
}

template <bool MASKED>
__device__ __forceinline__ void pv_chunk(const ushort* __restrict__ kbuf, const ushort* __restrict__ vbuf,
                                         int kc, ushort* __restrict__ Pb,
                                         int l15, int lhi, int qrow,
                                         const bf16x8* q1f, const bf16x8* q2f,
                                         float c1, float c2, f32x4* o) {
    bf16x8 kf[2][4];
    load_k_frags(kbuf, l15, lhi, kf);
    bf16x8 vf[8];
    const char* vB = (const char*)vbuf;
#pragma unroll
    for (int dt = 0; dt < 8; ++dt) {
        const int d = dt * 16 + l15;
        vf[dt] = *(const bf16x8*)(vB + d * 64 + ((lhi * 16) ^ (((d >> 1) & 3) << 4)));
    }
    f32x4 s1[2], s2[2];
#pragma unroll
    for (int n2 = 0; n2 < 2; ++n2) {
        s1[n2] = (f32x4){0.f, 0.f, 0.f, 0.f};
        s2[n2] = (f32x4){0.f, 0.f, 0.f, 0.f};
#pragma unroll
        for (int c = 0; c < 4; ++c) {
            s1[n2] = MFMA16(kf[n2][c], q1f[c], s1[n2]);
            s2[n2] = MFMA16(kf[n2][c], q2f[c], s2[n2]);
        }
    }
    const int kbase = kc + lhi * 4;
#pragma unroll
    for (int n2 = 0; n2 < 2; ++n2) {
        float p[4];
#pragma unroll
        for (int r = 0; r < 4; ++r) {
            float e1 = exp2_fast(s1[n2][r]) * c1;
            float e2 = exp2_fast(s2[n2][r]) * c2;
            float pv = fmaxf(e1 - e2, 0.f);
            if (MASKED) pv = ((kbase + n2 * 16 + r) <= qrow) ? pv : 0.f;
            p[r] = pv;
        }
        uint2 w;
        w.x = cvtpk(p[0], p[1]);
        w.y = cvtpk(p[2], p[3]);
        *(uint2*)(Pb + l15 * 40 + n2 * 16 + lhi * 4) = w;
    }
    asm volatile("s_waitcnt lgkmcnt(0)" ::: "memory");
    bf16x8 pf = *(const bf16x8*)(Pb + l15 * 40 + lhi * 8);
#pragma unroll
    for (int dt = 0; dt < 8; ++dt)
        o[dt] = MFMA16(pf, vf[dt], o[dt]);
}

__global__ __launch_bounds__(256) void attn_pv_k(const ushort* __restrict__ qkv,
                                                 const ushort* __restrict__ vtb,
                                                 const float* __restrict__ sums,
                                                 ushort* __restrict__ op0,
                                                 ushort* __restrict__ op1) {
    __shared__ ushort Kbuf[2 * 4096];
    __shared__ ushort Vbuf[2 * 4096];
    __shared__ ushort P[4][16][40];
    const int bid = blockIdx.x;
    const int strip = 127 - (bid >> 3);
    const int cs = (bid >> 2) & 1;
    const int hg = bid & 3;
    const int q0 = strip << 4;
    const int lane = threadIdx.x & 63, wid = threadIdx.x >> 6;
    const int h = hg * 4 + wid;
    const int l15 = lane & 15, lhi = lane >> 4;
    const int qrow = q0 + l15;
    const ushort* kb = qkv + 4096;

    bf16x8 q1f[4], q2f[4];
    {
        size_t base = (size_t)qrow * LDQ + h * 128 + lhi * 8;
#pragma unroll
        for (int c = 0; c < 4; ++c) {
            q1f[c] = *(const bf16x8*)(qkv + base + c * 32);
            q2f[c] = *(const bf16x8*)(qkv + base + 2048 + c * 32);
        }
    }

    const float sum1 = sums[(size_t)(0 * 16 + h) * 2048 + qrow] + sums[(size_t)(2 * 16 + h) * 2048 + qrow];
    const float sum2 = sums[(size_t)(1 * 16 + h) * 2048 + qrow] + sums[(size_t)(3 * 16 + h) * 2048 + qrow];
    const float inv_denom = 1.0f / (0.5f + 1e-8f);
    const float c1 = inv_denom / sum1;
    const float c2 = 0.5f * inv_denom / sum2;

    f32x4 o[8];
#pragma unroll
    for (int dt = 0; dt < 8; ++dt) o[dt] = (f32x4){0.f, 0.f, 0.f, 0.f};

    const int nchunk = (strip >> 1) + 1;
    const int ndiag = nchunk - 1;
    const int nch = (nchunk - cs + 1) >> 1;

    if (nch > 0) {
        stage_k_chunk(kb, cs * 32, Kbuf, wid, lane);
        stage_v_chunk(vtb, cs * 32, Vbuf, wid, lane);
    }
    __syncthreads();
    for (int i = 0; i < nch; ++i) {
        const int ch = cs + 2 * i, kc = ch << 5;
        if (i + 1 < nch) {
            stage_k_chunk(kb, kc + 64, Kbuf + ((i + 1) & 1) * 4096, wid, lane);
            stage_v_chunk(vtb, kc + 64, Vbuf + ((i + 1) & 1) * 4096, wid, lane);
        }
        const ushort* kcur = Kbuf + (i & 1) * 4096;
        const ushort* vcur = Vbuf + (i & 1) * 4096;
        ushort* Pb = &P[wid][0][0];
        if (ch == ndiag)
            pv_chunk<true>(kcur, vcur, kc, Pb, l15, lhi, qrow, q1f, q2f, c1, c2, o);
        else
            pv_chunk<false>(kcur, vcur, kc, Pb, l15, lhi, qrow, q1f, q2f, c1, c2, o);
        __syncthreads();
    }

    ushort* op = cs ? op1 : op0;
#pragma unroll
    for (int dt = 0; dt < 8; ++dt)
#pragma unroll
        for (int r = 0; r < 4; ++r)
            op[(size_t)(q0 + lhi * 4 + r) * 2048 + h * 128 + dt * 16 + l15] = f2bf(o[dt][r]);
}

// ---------------- combine partial O halves: aob = bf16(op0 + op1) ----------------
__device__ __forceinline__ unsigned int addbf2(unsigned int a, unsigned int b) {
    float alo = bf2f((ushort)a), ahi = bf2f((ushort)(a >> 16));
    float blo = bf2f((ushort)b), bhi = bf2f((ushort)(b >> 16));
    return (unsigned int)f2bf(alo + blo) | ((unsigned int)f2bf(ahi + bhi) << 16);
}
__global__ void combine_k(const ushort* __restrict__ o0, const ushort* __restrict__ o1,
                          ushort* __restrict__ out, int n8) {
    int i = blockIdx.x * blockDim.x + threadIdx.x;
    if (i >= n8) return;
    uint4 a = ((const uint4*)o0)[i];
    uint4 b = ((const uint4*)o1)[i];
    uint4 c;
    c.x = addbf2(a.x, b.x);
    c.y = addbf2(a.y, b.y);
    c.z = addbf2(a.z, b.z);
    c.w = addbf2(a.w, b.w);
    ((uint4*)out)[i] = c;
}

extern "C" void kernel_launch(void* const* d_in, const int* in_sizes, int n_in,
                              void* d_out, int out_size, void* d_ws, size_t ws_size,
                              hipStream_t stream) {
    const int S = 2048, HID = 2048;

    const float* x = (const float*)d_in[0];
    const float* fcos = (const float*)d_in[1];
    const float* fsin = (const float*)d_in[2];
    // d_in[3] = mask (causal, implicit)
    const float* q1w = (const float*)d_in[4];
    const float* q2w = (const float*)d_in[5];
    const float* kw = (const float*)d_in[6];
    const float* vw = (const float*)d_in[7];
    const float* ow = (const float*)d_in[8];

    ushort* xb = (ushort*)d_ws;                        // 8MB; reused as opart0
    ushort* btq = xb + (size_t)4194304;                // fused Bt: w1t|w2t|wkt|wvt (17MB)
    ushort* w1t = btq;                                 //   reused as opart1
    ushort* w2t = btq + (size_t)2048 * 2048;           //   reused as aob
    ushort* wkt = btq + (size_t)4096 * 2048;
    ushort* wvt = btq + (size_t)4224 * 2048;
    ushort* wot = btq + (size_t)8912896;               // 8MB
    ushort* qkvb = wot + (size_t)4194304;              // 17MB
    ushort* vtb = qkvb + (size_t)8912896;              // 0.5MB
    float* sums = (float*)(vtb + (size_t)262144);      // 0.5MB
    ushort* opart0 = xb;
    ushort* opart1 = w1t;
    ushort* aob = w2t;

    // 1. fused preprocessing: cvt(x) + 5 weight transpose/converts
    prep_k<<<dim3(16896), dim3(256), 0, stream>>>(x, xb, q1w, q2w, kw, vw, ow,
                                                  w1t, w2t, wkt, wvt, wot);

    // 2. fused QKV projection + RoPE + KSCALE + V-transpose (64x128 tiles, 1088 blocks = 4.25/CU)
    gemmqkv_k<<<dim3(1088), dim3(512), 0, stream>>>(xb, btq, qkvb, fcos, fsin, vtb);

    // 3. attention pass 1 (exp2-sums)
    attn_sums_k<<<dim3(1024), dim3(256), 0, stream>>>(qkvb, sums);

    // 4. attention pass 2 (PV partials)
    attn_pv_k<<<dim3(1024), dim3(256), 0, stream>>>(qkvb, vtb, sums, opart0, opart1);

    // 5. combine halves -> aob
    combine_k<<<dim3(2048), dim3(256), 0, stream>>>(opart0, opart1, aob, S * HID / 8);

    // 6. output projection (128x64 tiles -> 512 blocks = 2/CU)
    gemm_op_k<<<dim3(512), dim3(512), 0, stream>>>(aob, wot, (float*)d_out);
}

// Round 17
// 173.686 us; speedup vs baseline: 1.1351x; 1.1351x over previous
//
#include <hip/hip_runtime.h>
#include <hip/hip_bf16.h>

typedef __attribute__((ext_vector_type(8))) short bf16x8;
typedef __attribute__((ext_vector_type(4))) float f32x4;

#define MFMA16(a, b, c) __builtin_amdgcn_mfma_f32_16x16x32_bf16((a), (b), (c), 0, 0, 0)

#define LDQ 4352  // fused qkv row stride (2048+2048+128+128)
// K columns are pre-scaled by 1/sqrt(128)*log2(e) in the QKV GEMM epilogue,
// so attention probabilities are exp2(s) = v_exp_f32(s) directly.
#define KSCALE 0.12751743f

__device__ __forceinline__ ushort f2bf(float f) {
    unsigned int x = __float_as_uint(f);
    x += 0x7fffu + ((x >> 16) & 1u);
    return (ushort)(x >> 16);
}
__device__ __forceinline__ float bf2f(ushort u) {
    return __uint_as_float(((unsigned int)u) << 16);
}
__device__ __forceinline__ float exp2_fast(float x) {
    float r;
    asm("v_exp_f32 %0, %1" : "=v"(r) : "v"(x));
    return r;
}
__device__ __forceinline__ unsigned int cvtpk(float lo, float hi) {
    unsigned int r;
    asm("v_cvt_pk_bf16_f32 %0, %1, %2" : "=v"(r) : "v"(lo), "v"(hi));
    return r;
}

__device__ __forceinline__ void gload16(const ushort* g, ushort* l) {
    __builtin_amdgcn_global_load_lds((const __attribute__((address_space(1))) unsigned int*)g,
                                     (__attribute__((address_space(3))) unsigned int*)l, 16, 0, 0);
}

// ---------------- fused preprocessing: cvt(x) + 5 weight transposes ----------------
__global__ __launch_bounds__(256) void prep_k(const float* __restrict__ x, ushort* __restrict__ xb,
                                              const float* __restrict__ q1w, const float* __restrict__ q2w,
                                              const float* __restrict__ kw, const float* __restrict__ vw,
                                              const float* __restrict__ ow,
                                              ushort* __restrict__ w1t, ushort* __restrict__ w2t,
                                              ushort* __restrict__ wkt, ushort* __restrict__ wvt,
                                              ushort* __restrict__ wot) {
    int bid = blockIdx.x;
    if (bid < 4096) {
        int i = bid * 256 + threadIdx.x;
        float4 v = ((const float4*)x)[i];
        ushort4 u;
        u.x = f2bf(v.x); u.y = f2bf(v.y); u.z = f2bf(v.z); u.w = f2bf(v.w);
        ((ushort4*)xb)[i] = u;
        return;
    }
    bid -= 4096;
    const float* in;
    ushort* out;
    int C, TX;
    if (bid < 4096) { in = q1w; out = w1t; C = 2048; TX = 64; }
    else if (bid < 8192) { bid -= 4096; in = q2w; out = w2t; C = 2048; TX = 64; }
    else if (bid < 12288) { bid -= 8192; in = ow; out = wot; C = 2048; TX = 64; }
    else if (bid < 12544) { bid -= 12288; in = kw; out = wkt; C = 128; TX = 4; }
    else { bid -= 12544; in = vw; out = wvt; C = 128; TX = 4; }
    __shared__ ushort t[32][33];
    const int c0 = (bid % TX) * 32, r0 = (bid / TX) * 32;
    const int lx = threadIdx.x & 31, ly = threadIdx.x >> 5;
#pragma unroll
    for (int i = 0; i < 4; ++i)
        t[ly + i * 8][lx] = f2bf(in[(size_t)(r0 + ly + i * 8) * C + c0 + lx]);
    __syncthreads();
    const int sc = threadIdx.x & 15;
    const int sr = threadIdx.x >> 4;
#pragma unroll
    for (int j = 0; j < 2; ++j) {
        const int cc = sr + j * 16;
        unsigned int w = (unsigned int)t[2 * sc][cc] | ((unsigned int)t[2 * sc + 1][cc] << 16);
        *(unsigned int*)&out[(size_t)(c0 + cc) * 2048 + r0 + 2 * sc] = w;
    }
}

// ---------------- bf16 GEMM: 8 waves (2x4), 128x128 tile, BK=32, dbuf (QKV, fused) ----------------
// Measured tile/residency optimum: 256^2@0.5/CU=84us, 128^2@2.1/CU=58us, 64x128@4.25/CU=82us.
template <bool FUSE>
__global__ __launch_bounds__(512) void gemm8_k(const ushort* __restrict__ A, int lda,
                                               const ushort* __restrict__ Bt, int ldb,
                                               void* __restrict__ C, int ldc,
                                               int K, int nbx, int cbf,
                                               const float* __restrict__ cs,
                                               const float* __restrict__ sn,
                                               ushort* __restrict__ vtb) {
    __shared__ ushort As[2 * 4096];
    __shared__ ushort Bs[2 * 4096];
    const int tid = threadIdx.x;
    const int lane = tid & 63, wid = tid >> 6;
    const int cpx = (int)gridDim.x >> 3;
    const int swz = ((int)blockIdx.x & 7) * cpx + ((int)blockIdx.x >> 3);
    const int nt = swz / nbx;
    const int m0 = (swz % nbx) * 128, n0 = nt * 128;
    const int wr = wid >> 2, wc = wid & 3;
    const int l15 = lane & 15, lhi = lane >> 4;

    const int srow = tid >> 2;
    const int scol = (((tid & 3) ^ ((srow >> 1) & 3)) << 3);
    const ushort* gA = A + (size_t)(m0 + srow) * lda + scol;
    const ushort* gB = Bt + (size_t)(n0 + srow) * ldb + scol;
    ushort* lA = &As[wid * 512];
    ushort* lB = &Bs[wid * 512];

    f32x4 acc[4][2];
#pragma unroll
    for (int m = 0; m < 4; ++m)
#pragma unroll
        for (int n = 0; n < 2; ++n) acc[m][n] = (f32x4){0.f, 0.f, 0.f, 0.f};

    const int fcol = (lhi << 4) ^ (((l15 >> 1) & 3) << 4);

    gload16(gA, lA);
    gload16(gB, lB);
    __syncthreads();

    int cur = 0;
    for (int k0 = 0; k0 < K; k0 += 32) {
        if (k0 + 32 < K) {
            gload16(gA + k0 + 32, lA + (cur ^ 1) * 4096);
            gload16(gB + k0 + 32, lB + (cur ^ 1) * 4096);
        }
        const char* aB = (const char*)&As[cur * 4096];
        const char* bB = (const char*)&Bs[cur * 4096];
        bf16x8 af[4], bfr[2];
#pragma unroll
        for (int m = 0; m < 4; ++m)
            af[m] = *(const bf16x8*)(aB + (wr * 64 + m * 16 + l15) * 64 + fcol);
#pragma unroll
        for (int n = 0; n < 2; ++n)
            bfr[n] = *(const bf16x8*)(bB + (wc * 16 + n * 64 + l15) * 64 + fcol);
#pragma unroll
        for (int m = 0; m < 4; ++m)
#pragma unroll
            for (int n = 0; n < 2; ++n)
                acc[m][n] = MFMA16(af[m], bfr[n], acc[m][n]);
        __syncthreads();
        cur ^= 1;
    }

    if (FUSE) {
        if (nt == 33) {
#pragma unroll
            for (int m = 0; m < 4; ++m) {
                const int rb = m0 + wr * 64 + m * 16 + lhi * 4;
#pragma unroll
                for (int n = 0; n < 2; ++n) {
                    const int d = wc * 16 + n * 64 + l15;
                    uint2 w;
                    w.x = cvtpk(acc[m][n][0], acc[m][n][1]);
                    w.y = cvtpk(acc[m][n][2], acc[m][n][3]);
                    *(uint2*)(vtb + (size_t)d * 2048 + rb) = w;
                }
            }
        } else {
            const float scale = (nt == 32) ? KSCALE : 1.0f;
            ushort* out = (ushort*)C;
            const int d0 = wc * 16 + l15;
#pragma unroll
            for (int m = 0; m < 4; ++m) {
                const int rb = m0 + wr * 64 + m * 16 + lhi * 4;
#pragma unroll
                for (int r = 0; r < 4; ++r) {
                    const int row = rb + r;
                    float c0 = cs[row * 128 + d0], c1 = cs[row * 128 + d0 + 64];
                    float s0 = sn[row * 128 + d0], s1 = sn[row * 128 + d0 + 64];
                    float t0 = acc[m][0][r], t1 = acc[m][1][r];
                    out[(size_t)row * ldc + n0 + d0] = f2bf((t0 * c0 - t1 * s0) * scale);
                    out[(size_t)row * ldc + n0 + d0 + 64] = f2bf((t1 * c1 + t0 * s1) * scale);
                }
            }
        }
    } else {
#pragma unroll
        for (int m = 0; m < 4; ++m) {
            const int rb = m0 + wr * 64 + m * 16 + lhi * 4;
#pragma unroll
            for (int n = 0; n < 2; ++n) {
                const int col = n0 + wc * 16 + n * 64 + l15;
#pragma unroll
                for (int r = 0; r < 4; ++r) {
                    if (cbf)
                        ((ushort*)C)[(size_t)(rb + r) * ldc + col] = f2bf(acc[m][n][r]);
                    else
                        ((float*)C)[(size_t)(rb + r) * ldc + col] = acc[m][n][r];
                }
            }
        }
    }
}

// ---------------- out-proj GEMM: 128x64 tile, 512 blocks = 2 blocks/CU ----------------
__global__ __launch_bounds__(512) void gemm_op_k(const ushort* __restrict__ A,
                                                 const ushort* __restrict__ Bt,
                                                 float* __restrict__ C) {
    __shared__ ushort As[2 * 4096];  // [buf][128 rows][32 cols]
    __shared__ ushort Bs[2 * 2048];  // [buf][64 rows][32 cols]
    const int tid = threadIdx.x;
    const int lane = tid & 63, wid = tid >> 6;
    const int cpx = (int)gridDim.x >> 3;  // 64
    const int swz = ((int)blockIdx.x & 7) * cpx + ((int)blockIdx.x >> 3);
    const int m0 = (swz & 15) * 128, n0 = (swz >> 4) * 64;
    const int wr = wid >> 2, wc = wid & 3;
    const int l15 = lane & 15, lhi = lane >> 4;

    const int srow = tid >> 2;
    const int scol = (((tid & 3) ^ ((srow >> 1) & 3)) << 3);
    const ushort* gA = A + (size_t)(m0 + srow) * 2048 + scol;
    ushort* lA = &As[wid * 512];
    const int brow = wid * 16 + (lane >> 2);
    const int bcol = (((lane & 3) ^ ((brow >> 1) & 3)) << 3);
    const ushort* gB = Bt + (size_t)(n0 + brow) * 2048 + bcol;
    ushort* lB = &Bs[wid * 512];

    f32x4 acc[4];
#pragma unroll
    for (int m = 0; m < 4; ++m) acc[m] = (f32x4){0.f, 0.f, 0.f, 0.f};

    const int fcol = (lhi << 4) ^ (((l15 >> 1) & 3) << 4);

    gload16(gA, lA);
    if (wid < 4) gload16(gB, lB);
    __syncthreads();

    int cur = 0;
    for (int k0 = 0; k0 < 2048; k0 += 32) {
        if (k0 + 32 < 2048) {
            gload16(gA + k0 + 32, lA + (cur ^ 1) * 4096);
            if (wid < 4) gload16(gB + k0 + 32, lB + (cur ^ 1) * 2048);
        }
        const char* aB = (const char*)&As[cur * 4096];
        const char* bB = (const char*)&Bs[cur * 2048];
        bf16x8 af[4], bfr;
#pragma unroll
        for (int m = 0; m < 4; ++m)
            af[m] = *(const bf16x8*)(aB + (wr * 64 + m * 16 + l15) * 64 + fcol);
        bfr = *(const bf16x8*)(bB + (wc * 16 + l15) * 64 + fcol);
#pragma unroll
        for (int m = 0; m < 4; ++m)
            acc[m] = MFMA16(af[m], bfr, acc[m]);
        __syncthreads();
        cur ^= 1;
    }

    const int col = n0 + wc * 16 + l15;
#pragma unroll
    for (int m = 0; m < 4; ++m) {
        const int rb = m0 + wr * 64 + m * 16 + lhi * 4;
#pragma unroll
        for (int r = 0; r < 4; ++r)
            C[(size_t)(rb + r) * 2048 + col] = acc[m][r];
    }
}

// ---------------- differential MQA attention (round-12 proven form) ----------------

__device__ __forceinline__ void stage_k_chunk(const ushort* __restrict__ kb, int kc,
                                              ushort* __restrict__ kbuf, int wid, int lane) {
#pragma unroll
    for (int u = 0; u < 2; ++u) {
        const int w = wid * 2 + u;
        const int row = w * 4 + (lane >> 4);
        const int colb = ((lane & 15) * 16) ^ ((row & 7) << 4);
        gload16(kb + (size_t)(kc + row) * LDQ + (colb >> 1), kbuf + w * 512);
    }
}

__device__ __forceinline__ void stage_v_chunk(const ushort* __restrict__ vtb, int kc,
                                              ushort* __restrict__ vbuf, int wid, int lane) {
#pragma unroll
    for (int u = 0; u < 2; ++u) {
        const int w = wid * 2 + u;
        const int rowd = w * 16 + (lane >> 2);
        const int colb = ((lane & 3) * 16) ^ (((rowd >> 1) & 3) << 4);
        gload16(vtb + (size_t)rowd * 2048 + kc + (colb >> 1), vbuf + w * 512);
    }
}

__device__ __forceinline__ void load_k_frags(const ushort* __restrict__ kbuf, int l15, int lhi,
                                             bf16x8 kf[2][4]) {
    const char* kB = (const char*)kbuf;
#pragma unroll
    for (int n2 = 0; n2 < 2; ++n2) {
        const int r = n2 * 16 + l15;
#pragma unroll
        for (int c = 0; c < 4; ++c)
            kf[n2][c] = *(const bf16x8*)(kB + r * 256 + ((lhi * 16 + c * 64) ^ ((r & 7) << 4)));
    }
}

template <bool MASKED>
__device__ __forceinline__ void sums_chunk(const ushort* __restrict__ kbuf, int kc,
                                           int l15, int lhi, int qrow,
                                           const bf16x8* q1f, const bf16x8* q2f,
                                           float& sum1, float& sum2) {
    bf16x8 kf[2][4];
    load_k_frags(kbuf, l15, lhi, kf);
    f32x4 s1[2], s2[2];
#pragma unroll
    for (int n2 = 0; n2 < 2; ++n2) {
        s1[n2] = (f32x4){0.f, 0.f, 0.f, 0.f};
        s2[n2] = (f32x4){0.f, 0.f, 0.f, 0.f};
#pragma unroll
        for (int c = 0; c < 4; ++c) {
            s1[n2] = MFMA16(kf[n2][c], q1f[c], s1[n2]);
            s2[n2] = MFMA16(kf[n2][c], q2f[c], s2[n2]);
        }
    }
    const int kbase = kc + lhi * 4;
#pragma unroll
    for (int n2 = 0; n2 < 2; ++n2)
#pragma unroll
        for (int r = 0; r < 4; ++r) {
            float e1 = exp2_fast(s1[n2][r]);
            float e2 = exp2_fast(s2[n2][r]);
            if (MASKED) {
                bool ok = (kbase + n2 * 16 + r) <= qrow;
                e1 = ok ? e1 : 0.f;
                e2 = ok ? e2 : 0.f;
            }
            sum1 += e1;
            sum2 += e2;
        }
}

__global__ __launch_bounds__(256) void attn_sums_k(const ushort* __restrict__ qkv,
                                                   float* __restrict__ sums) {
    __shared__ ushort Kbuf[2 * 4096];
    const int bid = blockIdx.x;
    const int strip = 127 - (bid >> 3);
    const int cs = (bid >> 2) & 1;
    const int hg = bid & 3;
    const int q0 = strip << 4;
    const int lane = threadIdx.x & 63, wid = threadIdx.x >> 6;
    const int h = hg * 4 + wid;
    const int l15 = lane & 15, lhi = lane >> 4;
    const int qrow = q0 + l15;
    const ushort* kb = qkv + 4096;

    bf16x8 q1f[4], q2f[4];
    {
        size_t base = (size_t)qrow * LDQ + h * 128 + lhi * 8;
#pragma unroll
        for (int c = 0; c < 4; ++c) {
            q1f[c] = *(const bf16x8*)(qkv + base + c * 32);
            q2f[c] = *(const bf16x8*)(qkv + base + 2048 + c * 32);
        }
    }

    const int nchunk = (strip >> 1) + 1;
    const int ndiag = nchunk - 1;
    const int nch = (nchunk - cs + 1) >> 1;

    float sum1 = 0.f, sum2 = 0.f;
    if (nch > 0) stage_k_chunk(kb, cs * 32, Kbuf, wid, lane);
    __syncthreads();
    for (int i = 0; i < nch; ++i) {
        const int ch = cs + 2 * i, kc = ch << 5;
        if (i + 1 < nch) stage_k_chunk(kb, kc + 64, Kbuf + ((i + 1) & 1) * 4096, wid, lane);
        const ushort* kcur = Kbuf + (i & 1) * 4096;
        if (ch == ndiag)
            sums_chunk<true>(kcur, kc, l15, lhi, qrow, q1f, q2f, sum1, sum2);
        else
            sums_chunk<false>(kcur, kc, l15, lhi, qrow, q1f, q2f, sum1, sum2);
        __syncthreads();
    }

    sum1 += __shfl_xor(sum1, 16);
    sum1 += __shfl_xor(sum1, 32);
    sum2 += __shfl_xor(sum2, 16);
    sum2 += __shfl_xor(sum2, 32);

    if (lhi == 0) {
        sums[(size_t)((cs * 2 + 0) * 16 + h) * 2048 + qrow] = sum1;
        sums[(size_t)((cs * 2 + 1) * 16 + h) * 2048 + qrow] = sum2;
    }
}

template <bool MASKED>
__device__ __forceinline__ void pv_chunk(const ushort* __restrict__ kbuf, const ushort* __restrict__ vbuf,
                                         int kc, ushort* __restrict__ Pb,
                                         int l15, int lhi, int qrow,
                                         const bf16x8* q1f, const bf16x8* q2f,
                                         float c1, float c2, f32x4* o) {
    bf16x8 kf[2][4];
    load_k_frags(kbuf, l15, lhi, kf);
    bf16x8 vf[8];
    const char* vB = (const char*)vbuf;
#pragma unroll
    for (int dt = 0; dt < 8; ++dt) {
        const int d = dt * 16 + l15;
        vf[dt] = *(const bf16x8*)(vB + d * 64 + ((lhi * 16) ^ (((d >> 1) & 3) << 4)));
    }
    f32x4 s1[2], s2[2];
#pragma unroll
    for (int n2 = 0; n2 < 2; ++n2) {
        s1[n2] = (f32x4){0.f, 0.f, 0.f, 0.f};
        s2[n2] = (f32x4){0.f, 0.f, 0.f, 0.f};
#pragma unroll
        for (int c = 0; c < 4; ++c) {
            s1[n2] = MFMA16(kf[n2][c], q1f[c], s1[n2]);
            s2[n2] = MFMA16(kf[n2][c], q2f[c], s2[n2]);
        }
    }
    const int kbase = kc + lhi * 4;
#pragma unroll
    for (int n2 = 0; n2 < 2; ++n2) {
        float p[4];
#pragma unroll
        for (int r = 0; r < 4; ++r) {
            float e1 = exp2_fast(s1[n2][r]) * c1;
            float e2 = exp2_fast(s2[n2][r]) * c2;
            float pv = fmaxf(e1 - e2, 0.f);
            if (MASKED) pv = ((kbase + n2 * 16 + r) <= qrow) ? pv : 0.f;
            p[r] = pv;
        }
        uint2 w;
        w.x = cvtpk(p[0], p[1]);
        w.y = cvtpk(p[2], p[3]);
        *(uint2*)(Pb + l15 * 40 + n2 * 16 + lhi * 4) = w;
    }
    asm volatile("s_waitcnt lgkmcnt(0)" ::: "memory");
    bf16x8 pf = *(const bf16x8*)(Pb + l15 * 40 + lhi * 8);
#pragma unroll
    for (int dt = 0; dt < 8; ++dt)
        o[dt] = MFMA16(pf, vf[dt], o[dt]);
}

__global__ __launch_bounds__(256) void attn_pv_k(const ushort* __restrict__ qkv,
                                                 const ushort* __restrict__ vtb,
                                                 const float* __restrict__ sums,
                                                 ushort* __restrict__ op0,
                                                 ushort* __restrict__ op1) {
    __shared__ ushort Kbuf[2 * 4096];
    __shared__ ushort Vbuf[2 * 4096];
    __shared__ ushort P[4][16][40];
    const int bid = blockIdx.x;
    const int strip = 127 - (bid >> 3);
    const int cs = (bid >> 2) & 1;
    const int hg = bid & 3;
    const int q0 = strip << 4;
    const int lane = threadIdx.x & 63, wid = threadIdx.x >> 6;
    const int h = hg * 4 + wid;
    const int l15 = lane & 15, lhi = lane >> 4;
    const int qrow = q0 + l15;
    const ushort* kb = qkv + 4096;

    bf16x8 q1f[4], q2f[4];
    {
        size_t base = (size_t)qrow * LDQ + h * 128 + lhi * 8;
#pragma unroll
        for (int c = 0; c < 4; ++c) {
            q1f[c] = *(const bf16x8*)(qkv + base + c * 32);
            q2f[c] = *(const bf16x8*)(qkv + base + 2048 + c * 32);
        }
    }

    const float sum1 = sums[(size_t)(0 * 16 + h) * 2048 + qrow] + sums[(size_t)(2 * 16 + h) * 2048 + qrow];
    const float sum2 = sums[(size_t)(1 * 16 + h) * 2048 + qrow] + sums[(size_t)(3 * 16 + h) * 2048 + qrow];
    const float inv_denom = 1.0f / (0.5f + 1e-8f);
    const float c1 = inv_denom / sum1;
    const float c2 = 0.5f * inv_denom / sum2;

    f32x4 o[8];
#pragma unroll
    for (int dt = 0; dt < 8; ++dt) o[dt] = (f32x4){0.f, 0.f, 0.f, 0.f};

    const int nchunk = (strip >> 1) + 1;
    const int ndiag = nchunk - 1;
    const int nch = (nchunk - cs + 1) >> 1;

    if (nch > 0) {
        stage_k_chunk(kb, cs * 32, Kbuf, wid, lane);
        stage_v_chunk(vtb, cs * 32, Vbuf, wid, lane);
    }
    __syncthreads();
    for (int i = 0; i < nch; ++i) {
        const int ch = cs + 2 * i, kc = ch << 5;
        if (i + 1 < nch) {
            stage_k_chunk(kb, kc + 64, Kbuf + ((i + 1) & 1) * 4096, wid, lane);
            stage_v_chunk(vtb, kc + 64, Vbuf + ((i + 1) & 1) * 4096, wid, lane);
        }
        const ushort* kcur = Kbuf + (i & 1) * 4096;
        const ushort* vcur = Vbuf + (i & 1) * 4096;
        ushort* Pb = &P[wid][0][0];
        if (ch == ndiag)
            pv_chunk<true>(kcur, vcur, kc, Pb, l15, lhi, qrow, q1f, q2f, c1, c2, o);
        else
            pv_chunk<false>(kcur, vcur, kc, Pb, l15, lhi, qrow, q1f, q2f, c1, c2, o);
        __syncthreads();
    }

    ushort* op = cs ? op1 : op0;
#pragma unroll
    for (int dt = 0; dt < 8; ++dt)
#pragma unroll
        for (int r = 0; r < 4; ++r)
            op[(size_t)(q0 + lhi * 4 + r) * 2048 + h * 128 + dt * 16 + l15] = f2bf(o[dt][r]);
}

// ---------------- combine partial O halves: aob = bf16(op0 + op1) ----------------
__device__ __forceinline__ unsigned int addbf2(unsigned int a, unsigned int b) {
    float alo = bf2f((ushort)a), ahi = bf2f((ushort)(a >> 16));
    float blo = bf2f((ushort)b), bhi = bf2f((ushort)(b >> 16));
    return (unsigned int)f2bf(alo + blo) | ((unsigned int)f2bf(ahi + bhi) << 16);
}
__global__ void combine_k(const ushort* __restrict__ o0, const ushort* __restrict__ o1,
                          ushort* __restrict__ out, int n8) {
    int i = blockIdx.x * blockDim.x + threadIdx.x;
    if (i >= n8) return;
    uint4 a = ((const uint4*)o0)[i];
    uint4 b = ((const uint4*)o1)[i];
    uint4 c;
    c.x = addbf2(a.x, b.x);
    c.y = addbf2(a.y, b.y);
    c.z = addbf2(a.z, b.z);
    c.w = addbf2(a.w, b.w);
    ((uint4*)out)[i] = c;
}

extern "C" void kernel_launch(void* const* d_in, const int* in_sizes, int n_in,
                              void* d_out, int out_size, void* d_ws, size_t ws_size,
                              hipStream_t stream) {
    const int S = 2048, HID = 2048;

    const float* x = (const float*)d_in[0];
    const float* fcos = (const float*)d_in[1];
    const float* fsin = (const float*)d_in[2];
    // d_in[3] = mask (causal, implicit)
    const float* q1w = (const float*)d_in[4];
    const float* q2w = (const float*)d_in[5];
    const float* kw = (const float*)d_in[6];
    const float* vw = (const float*)d_in[7];
    const float* ow = (const float*)d_in[8];

    ushort* xb = (ushort*)d_ws;                        // 8MB; reused as opart0
    ushort* btq = xb + (size_t)4194304;                // fused Bt: w1t|w2t|wkt|wvt (17MB)
    ushort* w1t = btq;                                 //   reused as opart1
    ushort* w2t = btq + (size_t)2048 * 2048;           //   reused as aob
    ushort* wkt = btq + (size_t)4096 * 2048;
    ushort* wvt = btq + (size_t)4224 * 2048;
    ushort* wot = btq + (size_t)8912896;               // 8MB
    ushort* qkvb = wot + (size_t)4194304;              // 17MB
    ushort* vtb = qkvb + (size_t)8912896;              // 0.5MB
    float* sums = (float*)(vtb + (size_t)262144);      // 0.5MB
    ushort* opart0 = xb;
    ushort* opart1 = w1t;
    ushort* aob = w2t;

    // 1. fused preprocessing: cvt(x) + 5 weight transpose/converts
    prep_k<<<dim3(16896), dim3(256), 0, stream>>>(x, xb, q1w, q2w, kw, vw, ow,
                                                  w1t, w2t, wkt, wvt, wot);

    // 2. fused QKV projection + RoPE + KSCALE + V-transpose (128x128 tiles, 544 blocks)
    gemm8_k<true><<<dim3(544), dim3(512), 0, stream>>>(xb, HID, btq, HID, qkvb, LDQ, HID, 16, 1,
                                                       fcos, fsin, vtb);

    // 3. attention pass 1 (exp2-sums)
    attn_sums_k<<<dim3(1024), dim3(256), 0, stream>>>(qkvb, sums);

    // 4. attention pass 2 (PV partials)
    attn_pv_k<<<dim3(1024), dim3(256), 0, stream>>>(qkvb, vtb, sums, opart0, opart1);

    // 5. combine halves -> aob
    combine_k<<<dim3(2048), dim3(256), 0, stream>>>(opart0, opart1, aob, S * HID / 8);

    // 6. output projection (128x64 tiles -> 512 blocks = 2/CU)
    gemm_op_k<<<dim3(512), dim3(512), 0, stream>>>(aob, wot, (float*)d_out);
}